// Round 8
// baseline (610.706 us; speedup 1.0000x reference)
//
#include <hip/hip_runtime.h>
#include <hip/hip_cooperative_groups.h>

#define D_IN 128
#define HID 256
#define BKT_SHIFT 9
#define BKT_SIZE 512        // nodes per bucket (N<=65536 -> nbkt<=128)
#define CHUNK 4096          // edges per block in binning phases
#define PAD_SLACK (8 * BKT_SIZE)  // >= max total row padding per bucket (7*512)

typedef __attribute__((ext_vector_type(8))) short short8;   // 8 bf16 MFMA A/B frag
typedef __attribute__((ext_vector_type(4))) float floatx4;  // MFMA C/D frag

// fp32 -> bf16 (RNE), branch-free; inputs finite
static __device__ __forceinline__ unsigned short f2b(float f) {
  unsigned u = __float_as_uint(f);
  unsigned r = (u + 0x7fffu + ((u >> 16) & 1u)) >> 16;
  return (unsigned short)r;
}

static __device__ __forceinline__ void unpack8(uint4 v, float* f) {
  f[0] = __uint_as_float(v.x << 16); f[1] = __uint_as_float(v.x & 0xffff0000u);
  f[2] = __uint_as_float(v.y << 16); f[3] = __uint_as_float(v.y & 0xffff0000u);
  f[4] = __uint_as_float(v.z << 16); f[5] = __uint_as_float(v.z & 0xffff0000u);
  f[6] = __uint_as_float(v.w << 16); f[7] = __uint_as_float(v.w & 0xffff0000u);
}

static __device__ __forceinline__ void acc_fma(float* acc, uint4 v, float w) {
  float g[8];
  unpack8(v, g);
#pragma unroll
  for (int d = 0; d < 8; ++d) acc[d] = fmaf(g[d], w, acc[d]);
}

// ================= fused CSR build + dtype prep (cooperative, 6 phases) =================
// P0: blk0 zeros bkt_cnt | other blocks: x->bf16, W1->Wt1^T, W2->Wt2^T
// P1: per-chunk LDS bucket histogram -> bkt_cnt
// P2: blk0: exclusive scan of bucket counts -> bkt_start/bkt_cursor
// P3: per-chunk binning scatter -> ebuf (bucket-contiguous, 16KB windows)
// P4: per-bucket degree hist (LDS) -> dinv + padded row offsets (rowse, srs in LDS)
// P5: place {src, w=dinv[s]*dinv[d]} into padded CSR; fill pad slots {node, 0}

__global__ __launch_bounds__(256) void mega_build_kernel(
    const int* __restrict__ src, const int* __restrict__ dst, int E, int N, int nbkt,
    int* __restrict__ bkt_cnt, int* __restrict__ bkt_start, int* __restrict__ bkt_cursor,
    float* __restrict__ dinv, int2* __restrict__ rowse,
    int2* __restrict__ ebuf, int2* __restrict__ csr,
    const float4* __restrict__ x4, unsigned short* __restrict__ xb, int n4,
    const float* __restrict__ W1, unsigned short* __restrict__ Wt1,
    const float* __restrict__ W2, unsigned short* __restrict__ Wt2) {
  __shared__ int hist[BKT_SIZE];
  __shared__ int aux[BKT_SIZE];     // P3: bbase[128]; P4/P5: srs[512]
  __shared__ int scur[BKT_SIZE];
  __shared__ float sdinv[BKT_SIZE];
  __shared__ int wsums[4];
  __shared__ int w0tot;
  cooperative_groups::grid_group grid = cooperative_groups::this_grid();
  const int tid = threadIdx.x, bid = blockIdx.x, nblk = gridDim.x;
  const int lane = tid & 63;

  // ---- P0 ----
  if (bid == 0) {
    for (int i = tid; i < nbkt; i += 256) bkt_cnt[i] = 0;
  } else {
    const int stride = (nblk - 1) * 256;
    const int start = (bid - 1) * 256 + tid;
    for (int i = start; i < n4; i += stride) {
      float4 v = x4[i];
      ushort4 o; o.x = f2b(v.x); o.y = f2b(v.y); o.z = f2b(v.z); o.w = f2b(v.w);
      *(ushort4*)(xb + (size_t)i * 4) = o;
    }
    for (int e = start; e < D_IN * HID; e += stride) {
      int k = e >> 8, n = e & 255;
      Wt1[n * D_IN + k] = f2b(W1[e]);   // W1[128][256] -> Wt1[256][128]
    }
    for (int e = start; e < D_IN * HID; e += stride) {
      int k = e >> 7, n = e & 127;
      Wt2[n * HID + k] = f2b(W2[e]);    // W2[256][128] -> Wt2[128][256]
    }
  }
  grid.sync();

  // ---- P1 ----
  {
    if (tid < nbkt) hist[tid] = 0;
    __syncthreads();
    const int base = bid * CHUNK, end = min(base + CHUNK, E);
    for (int e = base + tid; e < end; e += 256)
      atomicAdd(&hist[dst[e] >> BKT_SHIFT], 1);
    __syncthreads();
    if (tid < nbkt && hist[tid] > 0) atomicAdd(&bkt_cnt[tid], hist[tid]);
  }
  grid.sync();

  // ---- P2 (block 0; nbkt <= 128, waves 0-1) ----
  if (bid == 0) {
    int v = 0, incl = 0;
    if (tid < 128) {
      v = (tid < nbkt) ? bkt_cnt[tid] : 0;
      incl = v;
#pragma unroll
      for (int off = 1; off < 64; off <<= 1) {
        int t = __shfl_up(incl, off);
        if (lane >= off) incl += t;
      }
      if (tid == 63) w0tot = incl;
    }
    __syncthreads();
    if (tid < 128) {
      int ex = incl - v + (tid >= 64 ? w0tot : 0);
      if (tid < nbkt) { bkt_start[tid] = ex; bkt_cursor[tid] = ex; }
      if (tid == 0) bkt_start[nbkt] = E;
    }
  }
  grid.sync();

  // ---- P3 ----
  {
    if (tid < nbkt) hist[tid] = 0;
    __syncthreads();
    const int base = bid * CHUNK, end = min(base + CHUNK, E);
    for (int e = base + tid; e < end; e += 256)
      atomicAdd(&hist[dst[e] >> BKT_SHIFT], 1);
    __syncthreads();
    if (tid < nbkt) {
      int c = hist[tid];
      aux[tid] = c > 0 ? atomicAdd(&bkt_cursor[tid], c) : 0;
      hist[tid] = 0;
    }
    __syncthreads();
    for (int e = base + tid; e < end; e += 256) {
      int d = dst[e];
      int b = d >> BKT_SHIFT;
      int off = atomicAdd(&hist[b], 1);
      ebuf[aux[b] + off] = make_int2(src[e], d);
    }
  }
  grid.sync();

  // ---- P4 ----
  if (bid < nbkt) {
    const int node0 = bid << BKT_SHIFT;
    const int nloc = min(BKT_SIZE, N - node0);
    const int ebeg = bkt_start[bid], eend = bkt_start[bid + 1];
    hist[tid] = 0; hist[tid + 256] = 0;
    __syncthreads();
    for (int e = ebeg + tid; e < eend; e += 256)
      atomicAdd(&hist[ebuf[e].y - node0], 1);
    __syncthreads();
    const int h0 = hist[2 * tid], h1 = hist[2 * tid + 1];
    const int p0 = (h0 + 7) & ~7, p1 = (h1 + 7) & ~7;
    const int s = p0 + p1;
    const int wid = tid >> 6;
    int incl = s;
#pragma unroll
    for (int off = 1; off < 64; off <<= 1) {
      int t = __shfl_up(incl, off);
      if (lane >= off) incl += t;
    }
    if (lane == 63) wsums[wid] = incl;
    __syncthreads();
    int wex = 0;
    for (int w = 0; w < wid; ++w) wex += wsums[w];
    const int ex = wex + incl - s;
    const int base = ebeg + bid * PAD_SLACK;  // fixed per-bucket csr region
    if (2 * tid < nloc) {
      float dv = rsqrtf((float)(h0 + 1));
      int st = base + ex;
      dinv[node0 + 2 * tid] = dv;
      rowse[node0 + 2 * tid] = make_int2(st, st + p0);
      aux[2 * tid] = st; sdinv[2 * tid] = dv; scur[2 * tid] = 0;
    }
    if (2 * tid + 1 < nloc) {
      float dv = rsqrtf((float)(h1 + 1));
      int st = base + ex + p0;
      dinv[node0 + 2 * tid + 1] = dv;
      rowse[node0 + 2 * tid + 1] = make_int2(st, st + p1);
      aux[2 * tid + 1] = st; sdinv[2 * tid + 1] = dv; scur[2 * tid + 1] = 0;
    }
  }
  grid.sync();  // all dinv visible before cross-bucket reads

  // ---- P5 ----
  if (bid < nbkt) {
    const int node0 = bid << BKT_SHIFT;
    const int nloc = min(BKT_SIZE, N - node0);
    const int ebeg = bkt_start[bid], eend = bkt_start[bid + 1];
    for (int e = ebeg + tid; e < eend; e += 256) {
      int2 ed = ebuf[e];
      int l = ed.y - node0;
      int pos = atomicAdd(&scur[l], 1);
      float w = sdinv[l] * dinv[ed.x];
      csr[aux[l] + pos] = make_int2(ed.x, __float_as_int(w));
    }
    __syncthreads();
    for (int l = tid; l < nloc; l += 256) {
      int deg = scur[l];
      int p = (deg + 7) & ~7;
      int s0 = aux[l];
      int2 pad = make_int2(node0 + l, 0);
      for (int q = s0 + deg; q < s0 + p; ++q) csr[q] = pad;
    }
  }
}

// ================= MFMA bf16 GEMM: H[M][N_COLS] = A[M][K] @ Wt[N_COLS][K]^T =================
// 4 waves/block, each wave 16 rows x CPB cols (CPB/16 C-tiles); A-frag read once per kt.
// Layouts (verified m89/m91): A[m=lane&15][k=quad*8+j]; B[k=quad*8+j][n=lane&15];
// C/D: row=quad*4+reg, col=lane&15.

template<int N_COLS, int CPB, int K, bool BIAS_RELU>
__global__ __launch_bounds__(256) void mfma_gemm_kernel(const unsigned short* __restrict__ A,
                                                        const unsigned short* __restrict__ Wt,
                                                        const float* __restrict__ bias,
                                                        unsigned short* __restrict__ H, int M) {
  constexpr int NT = CPB / 16;
  const int tid = threadIdx.x;
  const int wave = tid >> 6;
  const int lane = tid & 63;
  const int quad = lane >> 4;
  const int l16 = lane & 15;
  const int row0 = blockIdx.x * 64 + wave * 16;
  const int col0 = blockIdx.y * CPB;

  int arow = row0 + l16;
  if (arow >= M) arow = M - 1;  // tail: loads clamped, stores guarded
  const short8* ap = (const short8*)(A + (size_t)arow * K + quad * 8);
  const short8* bp = (const short8*)(Wt + (size_t)(col0 + l16) * K + quad * 8);
  constexpr int BSTEP = 2 * K;  // 16 rows of Wt in short8 units

  floatx4 acc[NT];
#pragma unroll
  for (int t = 0; t < NT; ++t) acc[t] = floatx4{0.f, 0.f, 0.f, 0.f};

#pragma unroll
  for (int kt = 0; kt < K / 32; ++kt) {
    short8 a = ap[kt * 4];
#pragma unroll
    for (int t = 0; t < NT; ++t) {
      short8 b = bp[kt * 4 + t * BSTEP];
      acc[t] = __builtin_amdgcn_mfma_f32_16x16x32_bf16(a, b, acc[t], 0, 0, 0);
    }
  }

#pragma unroll
  for (int t = 0; t < NT; ++t) {
    const int col = col0 + t * 16 + l16;
    const float bv = BIAS_RELU ? bias[col] : 0.f;
#pragma unroll
    for (int r = 0; r < 4; ++r) {
      const int row = row0 + quad * 4 + r;
      if (row < M) {
        float v = acc[t][r];
        if (BIAS_RELU) { v += bv; v = v > 0.f ? v : 0.f; }
        H[(size_t)row * N_COLS + col] = f2b(v);
      }
    }
  }
}

// ================= CSR aggregation (D=128 bf16), unroll-8, padded rows =================
// 16 lanes/node (uint4 = 8 bf16 per gather), 16 nodes/block; rowse = {start,end} per node.

template<bool SKIP_BIAS>
__global__ __launch_bounds__(256) void agg_kernel(const uint4* __restrict__ Hq,
                                                  const int2* __restrict__ rowse,
                                                  const int2* __restrict__ csr,
                                                  const float* __restrict__ dinv,
                                                  const float* __restrict__ skip,
                                                  const float* __restrict__ bias,
                                                  void* __restrict__ OUT, int n) {
  const int lane = threadIdx.x & 15;
  const int node = blockIdx.x * 16 + (threadIdx.x >> 4);
  if (node >= n) return;

  const float dv = dinv[node];
  float acc[8];
  {
    uint4 sv = Hq[(size_t)node * 16 + lane];
    float f[8];
    unpack8(sv, f);
    const float ws = dv * dv;
#pragma unroll
    for (int d = 0; d < 8; ++d) acc[d] = f[d] * ws;
  }

  const int2 se = rowse[node];
  for (int j = se.x; j < se.y; j += 8) {
    int4 p0 = *(const int4*)(csr + j);
    int4 p1 = *(const int4*)(csr + j + 2);
    int4 p2 = *(const int4*)(csr + j + 4);
    int4 p3 = *(const int4*)(csr + j + 6);
    uint4 v0 = Hq[(size_t)p0.x * 16 + lane];
    uint4 v1 = Hq[(size_t)p0.z * 16 + lane];
    uint4 v2 = Hq[(size_t)p1.x * 16 + lane];
    uint4 v3 = Hq[(size_t)p1.z * 16 + lane];
    uint4 v4 = Hq[(size_t)p2.x * 16 + lane];
    uint4 v5 = Hq[(size_t)p2.z * 16 + lane];
    uint4 v6 = Hq[(size_t)p3.x * 16 + lane];
    uint4 v7 = Hq[(size_t)p3.z * 16 + lane];
    acc_fma(acc, v0, __int_as_float(p0.y));
    acc_fma(acc, v1, __int_as_float(p0.w));
    acc_fma(acc, v2, __int_as_float(p1.y));
    acc_fma(acc, v3, __int_as_float(p1.w));
    acc_fma(acc, v4, __int_as_float(p2.y));
    acc_fma(acc, v5, __int_as_float(p2.w));
    acc_fma(acc, v6, __int_as_float(p3.y));
    acc_fma(acc, v7, __int_as_float(p3.w));
  }

  if (SKIP_BIAS) {
    const float* sp = skip + (size_t)node * 128 + lane * 8;
    const float* bp = bias + lane * 8;
    float4 s0 = *(const float4*)sp, s1 = *(const float4*)(sp + 4);
    float4 b0 = *(const float4*)bp, b1 = *(const float4*)(bp + 4);
    float* op = (float*)OUT + (size_t)node * 128 + lane * 8;
    *(float4*)op = make_float4(acc[0] + s0.x + b0.x, acc[1] + s0.y + b0.y,
                               acc[2] + s0.z + b0.z, acc[3] + s0.w + b0.w);
    *(float4*)(op + 4) = make_float4(acc[4] + s1.x + b1.x, acc[5] + s1.y + b1.y,
                                     acc[6] + s1.z + b1.z, acc[7] + s1.w + b1.w);
  } else {
    uint4 o;
    o.x = (unsigned)f2b(acc[0]) | ((unsigned)f2b(acc[1]) << 16);
    o.y = (unsigned)f2b(acc[2]) | ((unsigned)f2b(acc[3]) << 16);
    o.z = (unsigned)f2b(acc[4]) | ((unsigned)f2b(acc[5]) << 16);
    o.w = (unsigned)f2b(acc[6]) | ((unsigned)f2b(acc[7]) << 16);
    ((uint4*)OUT)[(size_t)node * 16 + lane] = o;
  }
}

// ================= launch =================

extern "C" void kernel_launch(void* const* d_in, const int* in_sizes, int n_in,
                              void* d_out, int out_size, void* d_ws, size_t ws_size,
                              hipStream_t stream) {
  const float* x  = (const float*)d_in[0];
  const int*   ei = (const int*)d_in[1];
  const float* W1 = (const float*)d_in[2];
  const float* b1 = (const float*)d_in[3];
  const float* W2 = (const float*)d_in[4];
  const float* b2 = (const float*)d_in[5];
  float* out = (float*)d_out;

  int N = in_sizes[0] / D_IN;
  int E = in_sizes[1] / 2;
  const int* srcA = ei;
  const int* dstA = ei + E;
  int NBKT = (N + BKT_SIZE - 1) >> BKT_SHIFT;      // 98 for N=50000 (<=128)
  const int NCHUNK = (E + CHUNK - 1) / CHUNK;      // 391
  int GRID = NCHUNK > NBKT ? NCHUNK : NBKT;
  if (GRID < 2) GRID = 2;

  // ---- workspace (256B aligned) ----
  char* ws = (char*)d_ws;
  size_t off = 0;
  auto alloc = [&](size_t bytes) { void* p = ws + off; off = (off + bytes + 255) & ~(size_t)255; return p; };
  int*            bkt_cnt    = (int*)           alloc((size_t)NBKT * 4);
  int*            bkt_start  = (int*)           alloc((size_t)(NBKT + 1) * 4);
  int*            bkt_cursor = (int*)           alloc((size_t)NBKT * 4);
  float*          dinv       = (float*)         alloc((size_t)N * 4);
  int2*           rowse      = (int2*)          alloc((size_t)N * 8);
  int2*           ebuf       = (int2*)          alloc((size_t)E * 8);
  int2*           csr        = (int2*)          alloc(((size_t)E + (size_t)NBKT * PAD_SLACK) * 8);
  unsigned short* xb         = (unsigned short*)alloc((size_t)N * D_IN * 2);
  unsigned short* aggx       = (unsigned short*)alloc((size_t)N * D_IN * 2);
  unsigned short* h          = (unsigned short*)alloc((size_t)N * HID * 2);
  unsigned short* tb         = (unsigned short*)alloc((size_t)N * D_IN * 2);
  unsigned short* Wt1        = (unsigned short*)alloc((size_t)D_IN * HID * 2);
  unsigned short* Wt2        = (unsigned short*)alloc((size_t)D_IN * HID * 2);

  // 1) fused CSR build + prep (cooperative, 6 grid-synced phases)
  {
    int n4 = N * D_IN / 4;
    void* args[] = {(void*)&srcA, (void*)&dstA, (void*)&E, (void*)&N, (void*)&NBKT,
                    (void*)&bkt_cnt, (void*)&bkt_start, (void*)&bkt_cursor,
                    (void*)&dinv, (void*)&rowse, (void*)&ebuf, (void*)&csr,
                    (void*)&x, (void*)&xb, (void*)&n4,
                    (void*)&W1, (void*)&Wt1, (void*)&W2, (void*)&Wt2};
    hipLaunchCooperativeKernel((const void*)mega_build_kernel, dim3(GRID), dim3(256),
                               args, 0, stream);
  }

  // 2) aggx = Â x
  agg_kernel<false><<<(N + 15) / 16, 256, 0, stream>>>((const uint4*)xb, rowse, csr,
                                                       dinv, nullptr, nullptr, aggx, N);
  // 3) h = relu(aggx @ W1 + b1)   (full 256-col block; A read once)
  mfma_gemm_kernel<HID, HID, D_IN, true>
      <<<dim3((N + 63) / 64, 1), 256, 0, stream>>>(aggx, Wt1, b1, h, N);
  // 4) t = h @ W2                  (full 128-col block; A read once)
  mfma_gemm_kernel<D_IN, D_IN, HID, false>
      <<<dim3((N + 63) / 64, 1), 256, 0, stream>>>(h, Wt2, nullptr, tb, N);
  // 5) out = Â t + x + b2
  agg_kernel<true><<<(N + 15) / 16, 256, 0, stream>>>((const uint4*)tb, rowse, csr,
                                                      dinv, x, b2, out, N);
}

// Round 9
// 355.292 us; speedup vs baseline: 1.7189x; 1.7189x over previous
//
#include <hip/hip_runtime.h>

#define D_IN 128
#define HID 256
#define BKT_SHIFT 9
#define BKT_SIZE 512        // nodes per bucket; requires N <= 65536 (pack: src<<9|l)
#define CHUNK 4096          // edges per block in binning phases
#define PAD_SLACK 4096      // per-bucket csr slack >= max pad (7*512=3584)

typedef __attribute__((ext_vector_type(8))) short short8;   // 8 bf16 MFMA A/B frag
typedef __attribute__((ext_vector_type(4))) float floatx4;  // MFMA C/D frag

// fp32 -> bf16 (RNE), branch-free; inputs finite
static __device__ __forceinline__ unsigned short f2b(float f) {
  unsigned u = __float_as_uint(f);
  unsigned r = (u + 0x7fffu + ((u >> 16) & 1u)) >> 16;
  return (unsigned short)r;
}

static __device__ __forceinline__ void unpack8(uint4 v, float* f) {
  f[0] = __uint_as_float(v.x << 16); f[1] = __uint_as_float(v.x & 0xffff0000u);
  f[2] = __uint_as_float(v.y << 16); f[3] = __uint_as_float(v.y & 0xffff0000u);
  f[4] = __uint_as_float(v.z << 16); f[5] = __uint_as_float(v.z & 0xffff0000u);
  f[6] = __uint_as_float(v.w << 16); f[7] = __uint_as_float(v.w & 0xffff0000u);
}

static __device__ __forceinline__ void acc_fma(float* acc, uint4 v, float w) {
  float g[8];
  unpack8(v, g);
#pragma unroll
  for (int d = 0; d < 8; ++d) acc[d] = fmaf(g[d], w, acc[d]);
}

// ================= CSR build (separate dispatches; no grid.sync) =================

// P1a: bucket histogram (LDS-staged)
__global__ __launch_bounds__(256) void bin_hist_kernel(const int* __restrict__ dst,
                                                       int* __restrict__ bkt_cnt,
                                                       int E, int nbkt) {
  __shared__ int hist[128];
  const int tid = threadIdx.x;
  if (tid < nbkt) hist[tid] = 0;
  __syncthreads();
  const int base = blockIdx.x * CHUNK;
  const int end = min(base + CHUNK, E);
  for (int e = base + tid; e < end; e += 256)
    atomicAdd(&hist[dst[e] >> BKT_SHIFT], 1);
  __syncthreads();
  if (tid < nbkt && hist[tid] > 0) atomicAdd(&bkt_cnt[tid], hist[tid]);
}

// P1b: exclusive scan of bucket counts (nbkt <= 128); init cursors; dinv sentinel
__global__ __launch_bounds__(128) void bkt_scan_kernel(const int* __restrict__ bkt_cnt,
                                                       int* __restrict__ bkt_start,
                                                       int* __restrict__ bkt_cursor,
                                                       float* __restrict__ dinv,
                                                       int nbkt, int E, int N) {
  __shared__ int w0tot;
  const int tid = threadIdx.x;
  const int lane = tid & 63, wid = tid >> 6;
  int v = (tid < nbkt) ? bkt_cnt[tid] : 0;
  int incl = v;
#pragma unroll
  for (int off = 1; off < 64; off <<= 1) {
    int t = __shfl_up(incl, off);
    if (lane >= off) incl += t;
  }
  if (wid == 0 && lane == 63) w0tot = incl;
  __syncthreads();
  int ex = incl - v + (wid ? w0tot : 0);
  if (tid < nbkt) { bkt_start[tid] = ex; bkt_cursor[tid] = ex; }
  if (tid == 0) { bkt_start[nbkt] = E; dinv[N] = 0.f; }  // sentinel: pad slots weight 0
}

// P1c: bin edges into bucket-contiguous runs, packed u = (src<<9)|(dst&511)
__global__ __launch_bounds__(256) void bin_scatter_kernel(const int* __restrict__ src,
                                                          const int* __restrict__ dst,
                                                          int* __restrict__ bkt_cursor,
                                                          int* __restrict__ ebuf,
                                                          int E, int nbkt) {
  __shared__ int hist[128];
  __shared__ int bbase[128];
  const int tid = threadIdx.x;
  if (tid < nbkt) hist[tid] = 0;
  __syncthreads();
  const int base = blockIdx.x * CHUNK;
  const int end = min(base + CHUNK, E);
  for (int e = base + tid; e < end; e += 256)
    atomicAdd(&hist[dst[e] >> BKT_SHIFT], 1);
  __syncthreads();
  if (tid < nbkt) {
    int c = hist[tid];
    bbase[tid] = c > 0 ? atomicAdd(&bkt_cursor[tid], c) : 0;
    hist[tid] = 0;  // reuse as intra-block cursor
  }
  __syncthreads();
  for (int e = base + tid; e < end; e += 256) {
    int d = dst[e];
    int b = d >> BKT_SHIFT;
    int off = atomicAdd(&hist[b], 1);
    ebuf[bbase[b] + off] = (src[e] << BKT_SHIFT) | (d & (BKT_SIZE - 1));
  }
}

// P2 (fused): per-bucket degree hist -> dinv + rowse; place src into padded CSR; pad fill.
// CSR region for bucket b: [bkt_start[b] + b*PAD_SLACK, ...) — fixed, no global scan needed.
__global__ __launch_bounds__(256) void bucket_build_kernel(const int* __restrict__ ebuf,
                                                           const int* __restrict__ bkt_start,
                                                           float* __restrict__ dinv,
                                                           int2* __restrict__ rowse,
                                                           int* __restrict__ csr,
                                                           int N, int nbkt) {
  __shared__ int hist[BKT_SIZE];
  __shared__ int srs[BKT_SIZE];
  __shared__ int wsums[4];
  const int b = blockIdx.x;
  const int tid = threadIdx.x;
  const int node0 = b << BKT_SHIFT;
  const int nloc = min(BKT_SIZE, N - node0);
  const int ebeg = bkt_start[b], eend = bkt_start[b + 1];

  hist[tid] = 0; hist[tid + 256] = 0;
  __syncthreads();
  for (int e = ebeg + tid; e < eend; e += 256)
    atomicAdd(&hist[ebuf[e] & (BKT_SIZE - 1)], 1);
  __syncthreads();

  // padded (multiple-of-8) 512-wide exclusive scan, 2 elems/thread
  const int h0 = hist[2 * tid], h1 = hist[2 * tid + 1];
  const int p0 = (h0 + 7) & ~7, p1 = (h1 + 7) & ~7;
  const int s = p0 + p1;
  const int lane = tid & 63, wid = tid >> 6;
  int incl = s;
#pragma unroll
  for (int off = 1; off < 64; off <<= 1) {
    int t = __shfl_up(incl, off);
    if (lane >= off) incl += t;
  }
  if (lane == 63) wsums[wid] = incl;
  __syncthreads();
  int wex = 0;
  for (int w = 0; w < wid; ++w) wex += wsums[w];
  const int ex = wex + incl - s;
  const int base = ebeg + b * PAD_SLACK;
  if (2 * tid < nloc) {
    int st = base + ex;
    dinv[node0 + 2 * tid] = rsqrtf((float)(h0 + 1));
    rowse[node0 + 2 * tid] = make_int2(st, st + p0);
    srs[2 * tid] = st;
  }
  if (2 * tid + 1 < nloc) {
    int st = base + ex + p0;
    dinv[node0 + 2 * tid + 1] = rsqrtf((float)(h1 + 1));
    rowse[node0 + 2 * tid + 1] = make_int2(st, st + p1);
    srs[2 * tid + 1] = st;
  }
  hist[2 * tid] = 0; hist[2 * tid + 1] = 0;  // reuse as per-node cursors
  __syncthreads();

  for (int e = ebeg + tid; e < eend; e += 256) {
    int u = ebuf[e];
    int l = u & (BKT_SIZE - 1);
    int pos = atomicAdd(&hist[l], 1);
    csr[srs[l] + pos] = u >> BKT_SHIFT;
  }
  __syncthreads();
  for (int l = tid; l < nloc; l += 256) {
    int deg = hist[l];
    int p = (deg + 7) & ~7;
    int s0 = srs[l];
    for (int q = s0 + deg; q < s0 + p; ++q) csr[q] = N;  // sentinel: dinv[N]=0
  }
}

// ================= fused conversions: x->bf16, W1->Wt1, W2->Wt2 =================

__global__ __launch_bounds__(256) void prep_kernel(const float4* __restrict__ x4,
                                                   unsigned short* __restrict__ xb, int n4,
                                                   const float* __restrict__ W1,
                                                   unsigned short* __restrict__ Wt1,
                                                   const float* __restrict__ W2,
                                                   unsigned short* __restrict__ Wt2) {
  const int nxblk = (n4 + 255) / 256;
  const int bid = blockIdx.x;
  if (bid < nxblk) {
    int i = bid * 256 + threadIdx.x;
    if (i >= n4) return;
    float4 v = x4[i];
    ushort4 o;
    o.x = f2b(v.x); o.y = f2b(v.y); o.z = f2b(v.z); o.w = f2b(v.w);
    *(ushort4*)(xb + (size_t)i * 4) = o;
  } else if (bid < nxblk + 128) {
    // W1[K=128][N=256] -> Wt1[N][K]
    int e = (bid - nxblk) * 256 + threadIdx.x;
    int k = e >> 8, n = e & 255;
    Wt1[(size_t)n * D_IN + k] = f2b(W1[e]);
  } else {
    // W2[K=256][N=128] -> Wt2[N][K]
    int e = (bid - nxblk - 128) * 256 + threadIdx.x;
    int k = e >> 7, n = e & 127;
    Wt2[(size_t)n * HID + k] = f2b(W2[e]);
  }
}

// ================= MFMA bf16 GEMM: H[M][N_COLS] = A[M][K] @ Wt[N_COLS][K]^T =================
// 4 waves/block, each wave 16 rows x N_COLS cols; A-frag read once per kt.
// Layouts (verified m89/m91): A[m=lane&15][k=quad*8+j]; B[k=quad*8+j][n=lane&15];
// C/D: row=quad*4+reg, col=lane&15.

template<int N_COLS, int K, bool BIAS_RELU>
__global__ __launch_bounds__(256) void mfma_gemm_kernel(const unsigned short* __restrict__ A,
                                                        const unsigned short* __restrict__ Wt,
                                                        const float* __restrict__ bias,
                                                        unsigned short* __restrict__ H, int M) {
  constexpr int NT = N_COLS / 16;
  const int tid = threadIdx.x;
  const int wave = tid >> 6;
  const int lane = tid & 63;
  const int quad = lane >> 4;
  const int l16 = lane & 15;
  const int row0 = blockIdx.x * 64 + wave * 16;

  int arow = row0 + l16;
  if (arow >= M) arow = M - 1;  // tail: loads clamped, stores guarded
  const short8* ap = (const short8*)(A + (size_t)arow * K + quad * 8);
  const short8* bp = (const short8*)(Wt + (size_t)l16 * K + quad * 8);
  constexpr int BSTEP = 2 * K;  // 16 rows of Wt in short8 units

  floatx4 acc[NT];
#pragma unroll
  for (int t = 0; t < NT; ++t) acc[t] = floatx4{0.f, 0.f, 0.f, 0.f};

#pragma unroll
  for (int kt = 0; kt < K / 32; ++kt) {
    short8 a = ap[kt * 4];
#pragma unroll
    for (int t = 0; t < NT; ++t) {
      short8 b = bp[kt * 4 + t * BSTEP];
      acc[t] = __builtin_amdgcn_mfma_f32_16x16x32_bf16(a, b, acc[t], 0, 0, 0);
    }
  }

#pragma unroll
  for (int t = 0; t < NT; ++t) {
    const int col = t * 16 + l16;
    const float bv = BIAS_RELU ? bias[col] : 0.f;
#pragma unroll
    for (int r = 0; r < 4; ++r) {
      const int row = row0 + quad * 4 + r;
      if (row < M) {
        float v = acc[t][r];
        if (BIAS_RELU) { v += bv; v = v > 0.f ? v : 0.f; }
        H[(size_t)row * N_COLS + col] = f2b(v);
      }
    }
  }
}

// ================= CSR aggregation (D=128 bf16), unroll-8, padded rows =================
// 16 lanes/node (uint4 = 8 bf16 per gather), 16 nodes/block; csr = src only (4B),
// w = dinv[s]*dinv[d] recomputed (dinv is L2-resident); pad sentinel N has dinv 0.

template<bool SKIP_BIAS>
__global__ __launch_bounds__(256) void agg_kernel(const uint4* __restrict__ Hq,
                                                  const int2* __restrict__ rowse,
                                                  const int* __restrict__ csr,
                                                  const float* __restrict__ dinv,
                                                  const float* __restrict__ skip,
                                                  const float* __restrict__ bias,
                                                  void* __restrict__ OUT, int n) {
  const int lane = threadIdx.x & 15;
  const int node = blockIdx.x * 16 + (threadIdx.x >> 4);
  if (node >= n) return;

  const float dv = dinv[node];
  float acc[8];
  {
    uint4 sv = Hq[(size_t)node * 16 + lane];
    float f[8];
    unpack8(sv, f);
    const float ws = dv * dv;
#pragma unroll
    for (int d = 0; d < 8; ++d) acc[d] = f[d] * ws;
  }

  const int2 se = rowse[node];
  for (int j = se.x; j < se.y; j += 8) {
    int4 c0 = *(const int4*)(csr + j);
    int4 c1 = *(const int4*)(csr + j + 4);
    float w0 = dinv[c0.x] * dv, w1 = dinv[c0.y] * dv;
    float w2 = dinv[c0.z] * dv, w3 = dinv[c0.w] * dv;
    float w4 = dinv[c1.x] * dv, w5 = dinv[c1.y] * dv;
    float w6 = dinv[c1.z] * dv, w7 = dinv[c1.w] * dv;
    uint4 v0 = Hq[(size_t)c0.x * 16 + lane];
    uint4 v1 = Hq[(size_t)c0.y * 16 + lane];
    uint4 v2 = Hq[(size_t)c0.z * 16 + lane];
    uint4 v3 = Hq[(size_t)c0.w * 16 + lane];
    uint4 v4 = Hq[(size_t)c1.x * 16 + lane];
    uint4 v5 = Hq[(size_t)c1.y * 16 + lane];
    uint4 v6 = Hq[(size_t)c1.z * 16 + lane];
    uint4 v7 = Hq[(size_t)c1.w * 16 + lane];
    acc_fma(acc, v0, w0);
    acc_fma(acc, v1, w1);
    acc_fma(acc, v2, w2);
    acc_fma(acc, v3, w3);
    acc_fma(acc, v4, w4);
    acc_fma(acc, v5, w5);
    acc_fma(acc, v6, w6);
    acc_fma(acc, v7, w7);
  }

  if (SKIP_BIAS) {
    const float* sp = skip + (size_t)node * 128 + lane * 8;
    const float* bp = bias + lane * 8;
    float4 s0 = *(const float4*)sp, s1 = *(const float4*)(sp + 4);
    float4 b0 = *(const float4*)bp, b1 = *(const float4*)(bp + 4);
    float* op = (float*)OUT + (size_t)node * 128 + lane * 8;
    *(float4*)op = make_float4(acc[0] + s0.x + b0.x, acc[1] + s0.y + b0.y,
                               acc[2] + s0.z + b0.z, acc[3] + s0.w + b0.w);
    *(float4*)(op + 4) = make_float4(acc[4] + s1.x + b1.x, acc[5] + s1.y + b1.y,
                                     acc[6] + s1.z + b1.z, acc[7] + s1.w + b1.w);
  } else {
    uint4 o;
    o.x = (unsigned)f2b(acc[0]) | ((unsigned)f2b(acc[1]) << 16);
    o.y = (unsigned)f2b(acc[2]) | ((unsigned)f2b(acc[3]) << 16);
    o.z = (unsigned)f2b(acc[4]) | ((unsigned)f2b(acc[5]) << 16);
    o.w = (unsigned)f2b(acc[6]) | ((unsigned)f2b(acc[7]) << 16);
    ((uint4*)OUT)[(size_t)node * 16 + lane] = o;
  }
}

// ================= launch =================

extern "C" void kernel_launch(void* const* d_in, const int* in_sizes, int n_in,
                              void* d_out, int out_size, void* d_ws, size_t ws_size,
                              hipStream_t stream) {
  const float* x  = (const float*)d_in[0];
  const int*   ei = (const int*)d_in[1];
  const float* W1 = (const float*)d_in[2];
  const float* b1 = (const float*)d_in[3];
  const float* W2 = (const float*)d_in[4];
  const float* b2 = (const float*)d_in[5];
  float* out = (float*)d_out;

  const int N = in_sizes[0] / D_IN;      // requires N <= 65536 (packed ebuf)
  const int E = in_sizes[1] / 2;
  const int* srcA = ei;
  const int* dstA = ei + E;
  const int NBKT = (N + BKT_SIZE - 1) >> BKT_SHIFT;  // 98 for N=50000
  const int NCHUNK = (E + CHUNK - 1) / CHUNK;        // 391

  // ---- workspace (256B aligned) ----
  char* ws = (char*)d_ws;
  size_t off = 0;
  auto alloc = [&](size_t bytes) { void* p = ws + off; off = (off + bytes + 255) & ~(size_t)255; return p; };
  int*            bkt_cnt    = (int*)           alloc((size_t)NBKT * 4);
  int*            bkt_start  = (int*)           alloc((size_t)(NBKT + 1) * 4);
  int*            bkt_cursor = (int*)           alloc((size_t)NBKT * 4);
  float*          dinv       = (float*)         alloc((size_t)(N + 1) * 4);  // +sentinel
  int2*           rowse      = (int2*)          alloc((size_t)N * 8);
  int*            ebuf       = (int*)           alloc((size_t)E * 4);
  int*            csr        = (int*)           alloc(((size_t)E + (size_t)NBKT * PAD_SLACK) * 4);
  unsigned short* xb         = (unsigned short*)alloc((size_t)(N + 1) * D_IN * 2);
  unsigned short* aggx       = (unsigned short*)alloc((size_t)N * D_IN * 2);
  unsigned short* h          = (unsigned short*)alloc((size_t)N * HID * 2);
  unsigned short* tb         = (unsigned short*)alloc((size_t)(N + 1) * D_IN * 2);
  unsigned short* Wt1        = (unsigned short*)alloc((size_t)D_IN * HID * 2);
  unsigned short* Wt2        = (unsigned short*)alloc((size_t)D_IN * HID * 2);

  // 1) CSR build: bucket hist -> scan -> bin -> fused per-bucket build
  hipMemsetAsync(bkt_cnt, 0, (size_t)NBKT * 4, stream);
  bin_hist_kernel<<<NCHUNK, 256, 0, stream>>>(dstA, bkt_cnt, E, NBKT);
  bkt_scan_kernel<<<1, 128, 0, stream>>>(bkt_cnt, bkt_start, bkt_cursor, dinv, NBKT, E, N);
  bin_scatter_kernel<<<NCHUNK, 256, 0, stream>>>(srcA, dstA, bkt_cursor, ebuf, E, NBKT);
  bucket_build_kernel<<<NBKT, 256, 0, stream>>>(ebuf, bkt_start, dinv, rowse, csr, N, NBKT);

  // 2) conversions
  {
    const int n4 = N * D_IN / 4;
    prep_kernel<<<(n4 + 255) / 256 + 256, 256, 0, stream>>>((const float4*)x, xb, n4,
                                                            W1, Wt1, W2, Wt2);
  }
  // 3) aggx = Â x
  agg_kernel<false><<<(N + 15) / 16, 256, 0, stream>>>((const uint4*)xb, rowse, csr,
                                                       dinv, nullptr, nullptr, aggx, N);
  // 4) h = relu(aggx @ W1 + b1)
  mfma_gemm_kernel<HID, D_IN, true><<<(N + 63) / 64, 256, 0, stream>>>(aggx, Wt1, b1, h, N);
  // 5) t = h @ W2
  mfma_gemm_kernel<D_IN, HID, false><<<(N + 63) / 64, 256, 0, stream>>>(h, Wt2, nullptr, tb, N);
  // 6) out = Â t + x + b2
  agg_kernel<true><<<(N + 15) / 16, 256, 0, stream>>>((const uint4*)tb, rowse, csr,
                                                      dinv, x, b2, out, N);
}

// Round 10
// 335.971 us; speedup vs baseline: 1.8177x; 1.0575x over previous
//
#include <hip/hip_runtime.h>

#define D_IN 128
#define HID 256
#define BKT_SHIFT 9
#define BKT_SIZE 512        // nodes per bucket; requires N <= 65536 (pack: src<<9|l)
#define CHUNK 4096          // edges per block in binning phases
#define PAD_SLACK 4096      // per-bucket csr slack >= max pad (7*512=3584)
#define LSTR 264            // LDS row stride (bf16); 528B = 33*16 keeps 16B alignment

typedef __attribute__((ext_vector_type(8))) short short8;   // 8 bf16 MFMA A/B frag
typedef __attribute__((ext_vector_type(4))) float floatx4;  // MFMA C/D frag

// fp32 -> bf16 (RNE), branch-free; inputs finite
static __device__ __forceinline__ unsigned short f2b(float f) {
  unsigned u = __float_as_uint(f);
  unsigned r = (u + 0x7fffu + ((u >> 16) & 1u)) >> 16;
  return (unsigned short)r;
}

static __device__ __forceinline__ void unpack8(uint4 v, float* f) {
  f[0] = __uint_as_float(v.x << 16); f[1] = __uint_as_float(v.x & 0xffff0000u);
  f[2] = __uint_as_float(v.y << 16); f[3] = __uint_as_float(v.y & 0xffff0000u);
  f[4] = __uint_as_float(v.z << 16); f[5] = __uint_as_float(v.z & 0xffff0000u);
  f[6] = __uint_as_float(v.w << 16); f[7] = __uint_as_float(v.w & 0xffff0000u);
}

static __device__ __forceinline__ void acc_fma(float* acc, uint4 v, float w) {
  float g[8];
  unpack8(v, g);
#pragma unroll
  for (int d = 0; d < 8; ++d) acc[d] = fmaf(g[d], w, acc[d]);
}

// ================= CSR build (separate dispatches; no grid.sync) =================

// P1a: bucket histogram (LDS-staged)
__global__ __launch_bounds__(256) void bin_hist_kernel(const int* __restrict__ dst,
                                                       int* __restrict__ bkt_cnt,
                                                       int E, int nbkt) {
  __shared__ int hist[128];
  const int tid = threadIdx.x;
  if (tid < nbkt) hist[tid] = 0;
  __syncthreads();
  const int base = blockIdx.x * CHUNK;
  const int end = min(base + CHUNK, E);
  for (int e = base + tid; e < end; e += 256)
    atomicAdd(&hist[dst[e] >> BKT_SHIFT], 1);
  __syncthreads();
  if (tid < nbkt && hist[tid] > 0) atomicAdd(&bkt_cnt[tid], hist[tid]);
}

// P1b: exclusive scan of bucket counts (nbkt <= 128); init cursors; dinv sentinel
__global__ __launch_bounds__(128) void bkt_scan_kernel(const int* __restrict__ bkt_cnt,
                                                       int* __restrict__ bkt_start,
                                                       int* __restrict__ bkt_cursor,
                                                       float* __restrict__ dinv,
                                                       int nbkt, int E, int N) {
  __shared__ int w0tot;
  const int tid = threadIdx.x;
  const int lane = tid & 63, wid = tid >> 6;
  int v = (tid < nbkt) ? bkt_cnt[tid] : 0;
  int incl = v;
#pragma unroll
  for (int off = 1; off < 64; off <<= 1) {
    int t = __shfl_up(incl, off);
    if (lane >= off) incl += t;
  }
  if (wid == 0 && lane == 63) w0tot = incl;
  __syncthreads();
  int ex = incl - v + (wid ? w0tot : 0);
  if (tid < nbkt) { bkt_start[tid] = ex; bkt_cursor[tid] = ex; }
  if (tid == 0) { bkt_start[nbkt] = E; dinv[N] = 0.f; }  // sentinel: pad slots weight 0
}

// P1c: bin edges into bucket-contiguous runs, packed u = (src<<9)|(dst&511)
__global__ __launch_bounds__(256) void bin_scatter_kernel(const int* __restrict__ src,
                                                          const int* __restrict__ dst,
                                                          int* __restrict__ bkt_cursor,
                                                          int* __restrict__ ebuf,
                                                          int E, int nbkt) {
  __shared__ int hist[128];
  __shared__ int bbase[128];
  const int tid = threadIdx.x;
  if (tid < nbkt) hist[tid] = 0;
  __syncthreads();
  const int base = blockIdx.x * CHUNK;
  const int end = min(base + CHUNK, E);
  for (int e = base + tid; e < end; e += 256)
    atomicAdd(&hist[dst[e] >> BKT_SHIFT], 1);
  __syncthreads();
  if (tid < nbkt) {
    int c = hist[tid];
    bbase[tid] = c > 0 ? atomicAdd(&bkt_cursor[tid], c) : 0;
    hist[tid] = 0;  // reuse as intra-block cursor
  }
  __syncthreads();
  for (int e = base + tid; e < end; e += 256) {
    int d = dst[e];
    int b = d >> BKT_SHIFT;
    int off = atomicAdd(&hist[b], 1);
    ebuf[bbase[b] + off] = (src[e] << BKT_SHIFT) | (d & (BKT_SIZE - 1));
  }
}

// P2 (fused): per-bucket degree hist -> dinv + rowse; place src into padded CSR; pad fill.
__global__ __launch_bounds__(256) void bucket_build_kernel(const int* __restrict__ ebuf,
                                                           const int* __restrict__ bkt_start,
                                                           float* __restrict__ dinv,
                                                           int2* __restrict__ rowse,
                                                           int* __restrict__ csr,
                                                           int N, int nbkt) {
  __shared__ int hist[BKT_SIZE];
  __shared__ int srs[BKT_SIZE];
  __shared__ int wsums[4];
  const int b = blockIdx.x;
  const int tid = threadIdx.x;
  const int node0 = b << BKT_SHIFT;
  const int nloc = min(BKT_SIZE, N - node0);
  const int ebeg = bkt_start[b], eend = bkt_start[b + 1];

  hist[tid] = 0; hist[tid + 256] = 0;
  __syncthreads();
  for (int e = ebeg + tid; e < eend; e += 256)
    atomicAdd(&hist[ebuf[e] & (BKT_SIZE - 1)], 1);
  __syncthreads();

  // padded (multiple-of-8) 512-wide exclusive scan, 2 elems/thread
  const int h0 = hist[2 * tid], h1 = hist[2 * tid + 1];
  const int p0 = (h0 + 7) & ~7, p1 = (h1 + 7) & ~7;
  const int s = p0 + p1;
  const int lane = tid & 63, wid = tid >> 6;
  int incl = s;
#pragma unroll
  for (int off = 1; off < 64; off <<= 1) {
    int t = __shfl_up(incl, off);
    if (lane >= off) incl += t;
  }
  if (lane == 63) wsums[wid] = incl;
  __syncthreads();
  int wex = 0;
  for (int w = 0; w < wid; ++w) wex += wsums[w];
  const int ex = wex + incl - s;
  const int base = ebeg + b * PAD_SLACK;
  if (2 * tid < nloc) {
    int st = base + ex;
    dinv[node0 + 2 * tid] = rsqrtf((float)(h0 + 1));
    rowse[node0 + 2 * tid] = make_int2(st, st + p0);
    srs[2 * tid] = st;
  }
  if (2 * tid + 1 < nloc) {
    int st = base + ex + p0;
    dinv[node0 + 2 * tid + 1] = rsqrtf((float)(h1 + 1));
    rowse[node0 + 2 * tid + 1] = make_int2(st, st + p1);
    srs[2 * tid + 1] = st;
  }
  hist[2 * tid] = 0; hist[2 * tid + 1] = 0;  // reuse as per-node cursors
  __syncthreads();

  for (int e = ebeg + tid; e < eend; e += 256) {
    int u = ebuf[e];
    int l = u & (BKT_SIZE - 1);
    int pos = atomicAdd(&hist[l], 1);
    csr[srs[l] + pos] = u >> BKT_SHIFT;
  }
  __syncthreads();
  for (int l = tid; l < nloc; l += 256) {
    int deg = hist[l];
    int p = (deg + 7) & ~7;
    int s0 = srs[l];
    for (int q = s0 + deg; q < s0 + p; ++q) csr[q] = N;  // sentinel: dinv[N]=0
  }
}

// ================= fused conversions: x->bf16, W1->Wt1, W2->Wt2 =================

__global__ __launch_bounds__(256) void prep_kernel(const float4* __restrict__ x4,
                                                   unsigned short* __restrict__ xb, int n4,
                                                   const float* __restrict__ W1,
                                                   unsigned short* __restrict__ Wt1,
                                                   const float* __restrict__ W2,
                                                   unsigned short* __restrict__ Wt2) {
  const int nxblk = (n4 + 255) / 256;
  const int bid = blockIdx.x;
  if (bid < nxblk) {
    int i = bid * 256 + threadIdx.x;
    if (i >= n4) return;
    float4 v = x4[i];
    ushort4 o;
    o.x = f2b(v.x); o.y = f2b(v.y); o.z = f2b(v.z); o.w = f2b(v.w);
    *(ushort4*)(xb + (size_t)i * 4) = o;
  } else if (bid < nxblk + 128) {
    // W1[K=128][N=256] -> Wt1[N][K]
    int e = (bid - nxblk) * 256 + threadIdx.x;
    int k = e >> 8, n = e & 255;
    Wt1[(size_t)n * D_IN + k] = f2b(W1[e]);
  } else {
    // W2[K=256][N=128] -> Wt2[N][K]
    int e = (bid - nxblk - 128) * 256 + threadIdx.x;
    int k = e >> 7, n = e & 127;
    Wt2[(size_t)n * HID + k] = f2b(W2[e]);
  }
}

// ================= fused MFMA GEMM1+GEMM2: T = relu(A@W1+b1) @ W2 =================
// 4 waves/block, 64 rows/block, 16 rows/wave. Phase 1: h-tile (16x256) via MFMA from
// global A/Wt1; epilogue -> wave-private LDS tile (no barrier: wave-local only).
// Phase 2: A-frags re-read from LDS, MFMA with Wt2 -> t-tile (16x128).
// Epilogue 2: t-tile -> LDS -> coalesced uint4 stores (full-line writes).
// Layouts (verified m89/m91): A[m=lane&15][k=quad*8+j]; B[k=quad*8+j][n=lane&15];
// C/D: row=quad*4+reg, col=lane&15.

__global__ __launch_bounds__(256) void gemm12_kernel(const unsigned short* __restrict__ A,
                                                     const unsigned short* __restrict__ Wt1,
                                                     const float* __restrict__ b1,
                                                     const unsigned short* __restrict__ Wt2,
                                                     unsigned short* __restrict__ T, int M) {
  __shared__ unsigned short hs[4][16][LSTR];
  const int tid = threadIdx.x;
  const int wave = tid >> 6;
  const int lane = tid & 63;
  const int quad = lane >> 4;
  const int l16 = lane & 15;
  const int row0 = blockIdx.x * 64 + wave * 16;

  int arow = row0 + l16;
  if (arow >= M) arow = M - 1;  // tail: loads clamped, final stores guarded
  const short8* ap = (const short8*)(A + (size_t)arow * D_IN + quad * 8);
  const short8* bp1 = (const short8*)(Wt1 + (size_t)l16 * D_IN + quad * 8);

  // ---- phase 1: h[16][256] = A[16][128] @ Wt1^T ----
  floatx4 acc1[16];
#pragma unroll
  for (int t = 0; t < 16; ++t) acc1[t] = floatx4{0.f, 0.f, 0.f, 0.f};
#pragma unroll
  for (int kt = 0; kt < 4; ++kt) {   // K=128
    short8 a = ap[kt * 4];
#pragma unroll
    for (int t = 0; t < 16; ++t) {
      short8 b = bp1[kt * 4 + t * 256];   // 16 Wt1 rows = 16*128/8 short8
      acc1[t] = __builtin_amdgcn_mfma_f32_16x16x32_bf16(a, b, acc1[t], 0, 0, 0);
    }
  }
  // epilogue 1: bias + relu + bf16 -> wave-private LDS tile
#pragma unroll
  for (int t = 0; t < 16; ++t) {
    const float bv = b1[t * 16 + l16];
#pragma unroll
    for (int r = 0; r < 4; ++r) {
      float v = acc1[t][r] + bv;
      v = v > 0.f ? v : 0.f;
      hs[wave][quad * 4 + r][t * 16 + l16] = f2b(v);
    }
  }

  // ---- phase 2: t[16][128] = h[16][256] @ Wt2^T (A-frags from LDS) ----
  const short8* bp2 = (const short8*)(Wt2 + (size_t)l16 * HID + quad * 8);
  floatx4 acc2[8];
#pragma unroll
  for (int t = 0; t < 8; ++t) acc2[t] = floatx4{0.f, 0.f, 0.f, 0.f};
#pragma unroll
  for (int kt = 0; kt < 8; ++kt) {   // K=256
    short8 a = *(const short8*)&hs[wave][l16][kt * 32 + quad * 8];
#pragma unroll
    for (int t = 0; t < 8; ++t) {
      short8 b = bp2[kt * 4 + t * 512];   // 16 Wt2 rows = 16*256/8 short8
      acc2[t] = __builtin_amdgcn_mfma_f32_16x16x32_bf16(a, b, acc2[t], 0, 0, 0);
    }
  }
  // epilogue 2: t-tile -> LDS (reuse; wave-local, in-order) -> coalesced stores
#pragma unroll
  for (int t = 0; t < 8; ++t) {
#pragma unroll
    for (int r = 0; r < 4; ++r)
      hs[wave][quad * 4 + r][t * 16 + l16] = f2b(acc2[t][r]);
  }
#pragma unroll
  for (int i = 0; i < 4; ++i) {   // 4 rows / instr: 16 lanes x 16B = one 256B row
    const int r = i * 4 + (lane >> 4);
    const int c = l16 * 8;
    const int row = row0 + r;
    uint4 v = *(const uint4*)&hs[wave][r][c];
    if (row < M) *(uint4*)&T[(size_t)row * D_IN + c] = v;
  }
}

// ================= CSR aggregation (D=128 bf16), unroll-8, padded rows =================
// 16 lanes/node (uint4 = 8 bf16 per gather), 16 nodes/block; csr = src only (4B),
// w = dinv[s]*dinv[d] recomputed (dinv L2-resident); pad sentinel N has dinv 0.

template<bool SKIP_BIAS>
__global__ __launch_bounds__(256) void agg_kernel(const uint4* __restrict__ Hq,
                                                  const int2* __restrict__ rowse,
                                                  const int* __restrict__ csr,
                                                  const float* __restrict__ dinv,
                                                  const float* __restrict__ skip,
                                                  const float* __restrict__ bias,
                                                  void* __restrict__ OUT, int n) {
  const int lane = threadIdx.x & 15;
  const int node = blockIdx.x * 16 + (threadIdx.x >> 4);
  if (node >= n) return;

  const float dv = dinv[node];
  float acc[8];
  {
    uint4 sv = Hq[(size_t)node * 16 + lane];
    float f[8];
    unpack8(sv, f);
    const float ws = dv * dv;
#pragma unroll
    for (int d = 0; d < 8; ++d) acc[d] = f[d] * ws;
  }

  const int2 se = rowse[node];
  for (int j = se.x; j < se.y; j += 8) {
    int4 c0 = *(const int4*)(csr + j);
    int4 c1 = *(const int4*)(csr + j + 4);
    float w0 = dinv[c0.x] * dv, w1 = dinv[c0.y] * dv;
    float w2 = dinv[c0.z] * dv, w3 = dinv[c0.w] * dv;
    float w4 = dinv[c1.x] * dv, w5 = dinv[c1.y] * dv;
    float w6 = dinv[c1.z] * dv, w7 = dinv[c1.w] * dv;
    uint4 v0 = Hq[(size_t)c0.x * 16 + lane];
    uint4 v1 = Hq[(size_t)c0.y * 16 + lane];
    uint4 v2 = Hq[(size_t)c0.z * 16 + lane];
    uint4 v3 = Hq[(size_t)c0.w * 16 + lane];
    uint4 v4 = Hq[(size_t)c1.x * 16 + lane];
    uint4 v5 = Hq[(size_t)c1.y * 16 + lane];
    uint4 v6 = Hq[(size_t)c1.z * 16 + lane];
    uint4 v7 = Hq[(size_t)c1.w * 16 + lane];
    acc_fma(acc, v0, w0);
    acc_fma(acc, v1, w1);
    acc_fma(acc, v2, w2);
    acc_fma(acc, v3, w3);
    acc_fma(acc, v4, w4);
    acc_fma(acc, v5, w5);
    acc_fma(acc, v6, w6);
    acc_fma(acc, v7, w7);
  }

  if (SKIP_BIAS) {
    const float* sp = skip + (size_t)node * 128 + lane * 8;
    const float* bp = bias + lane * 8;
    float4 s0 = *(const float4*)sp, s1 = *(const float4*)(sp + 4);
    float4 b0 = *(const float4*)bp, b1 = *(const float4*)(bp + 4);
    float* op = (float*)OUT + (size_t)node * 128 + lane * 8;
    *(float4*)op = make_float4(acc[0] + s0.x + b0.x, acc[1] + s0.y + b0.y,
                               acc[2] + s0.z + b0.z, acc[3] + s0.w + b0.w);
    *(float4*)(op + 4) = make_float4(acc[4] + s1.x + b1.x, acc[5] + s1.y + b1.y,
                                     acc[6] + s1.z + b1.z, acc[7] + s1.w + b1.w);
  } else {
    uint4 o;
    o.x = (unsigned)f2b(acc[0]) | ((unsigned)f2b(acc[1]) << 16);
    o.y = (unsigned)f2b(acc[2]) | ((unsigned)f2b(acc[3]) << 16);
    o.z = (unsigned)f2b(acc[4]) | ((unsigned)f2b(acc[5]) << 16);
    o.w = (unsigned)f2b(acc[6]) | ((unsigned)f2b(acc[7]) << 16);
    ((uint4*)OUT)[(size_t)node * 16 + lane] = o;
  }
}

// ================= launch =================

extern "C" void kernel_launch(void* const* d_in, const int* in_sizes, int n_in,
                              void* d_out, int out_size, void* d_ws, size_t ws_size,
                              hipStream_t stream) {
  const float* x  = (const float*)d_in[0];
  const int*   ei = (const int*)d_in[1];
  const float* W1 = (const float*)d_in[2];
  const float* b1 = (const float*)d_in[3];
  const float* W2 = (const float*)d_in[4];
  const float* b2 = (const float*)d_in[5];
  float* out = (float*)d_out;

  const int N = in_sizes[0] / D_IN;      // requires N <= 65536 (packed ebuf)
  const int E = in_sizes[1] / 2;
  const int* srcA = ei;
  const int* dstA = ei + E;
  const int NBKT = (N + BKT_SIZE - 1) >> BKT_SHIFT;  // 98 for N=50000
  const int NCHUNK = (E + CHUNK - 1) / CHUNK;        // 391

  // ---- workspace (256B aligned) ----
  char* ws = (char*)d_ws;
  size_t off = 0;
  auto alloc = [&](size_t bytes) { void* p = ws + off; off = (off + bytes + 255) & ~(size_t)255; return p; };
  int*            bkt_cnt    = (int*)           alloc((size_t)NBKT * 4);
  int*            bkt_start  = (int*)           alloc((size_t)(NBKT + 1) * 4);
  int*            bkt_cursor = (int*)           alloc((size_t)NBKT * 4);
  float*          dinv       = (float*)         alloc((size_t)(N + 1) * 4);  // +sentinel
  int2*           rowse      = (int2*)          alloc((size_t)N * 8);
  int*            ebuf       = (int*)           alloc((size_t)E * 4);
  int*            csr        = (int*)           alloc(((size_t)E + (size_t)NBKT * PAD_SLACK) * 4);
  unsigned short* xb         = (unsigned short*)alloc((size_t)(N + 1) * D_IN * 2);
  unsigned short* aggx       = (unsigned short*)alloc((size_t)N * D_IN * 2);
  unsigned short* tb         = (unsigned short*)alloc((size_t)(N + 1) * D_IN * 2);
  unsigned short* Wt1        = (unsigned short*)alloc((size_t)D_IN * HID * 2);
  unsigned short* Wt2        = (unsigned short*)alloc((size_t)D_IN * HID * 2);

  // 1) CSR build: bucket hist -> scan -> bin -> fused per-bucket build
  hipMemsetAsync(bkt_cnt, 0, (size_t)NBKT * 4, stream);
  bin_hist_kernel<<<NCHUNK, 256, 0, stream>>>(dstA, bkt_cnt, E, NBKT);
  bkt_scan_kernel<<<1, 128, 0, stream>>>(bkt_cnt, bkt_start, bkt_cursor, dinv, NBKT, E, N);
  bin_scatter_kernel<<<NCHUNK, 256, 0, stream>>>(srcA, dstA, bkt_cursor, ebuf, E, NBKT);
  bucket_build_kernel<<<NBKT, 256, 0, stream>>>(ebuf, bkt_start, dinv, rowse, csr, N, NBKT);

  // 2) conversions
  {
    const int n4 = N * D_IN / 4;
    prep_kernel<<<(n4 + 255) / 256 + 256, 256, 0, stream>>>((const float4*)x, xb, n4,
                                                            W1, Wt1, W2, Wt2);
  }
  // 3) aggx = Â x
  agg_kernel<false><<<(N + 15) / 16, 256, 0, stream>>>((const uint4*)xb, rowse, csr,
                                                       dinv, nullptr, nullptr, aggx, N);
  // 4) tb = relu(aggx @ W1 + b1) @ W2   (fused, h never touches HBM)
  gemm12_kernel<<<(N + 63) / 64, 256, 0, stream>>>(aggx, Wt1, b1, Wt2, tb, N);
  // 5) out = Â tb + x + b2
  agg_kernel<true><<<(N + 15) / 16, 256, 0, stream>>>((const uint4*)tb, rowse, csr,
                                                      dinv, x, b2, out, N);
}

// Round 11
// 296.697 us; speedup vs baseline: 2.0584x; 1.1324x over previous
//
#include <hip/hip_runtime.h>

#define D_IN 128
#define HID 256
#define BKT_SHIFT 9
#define BKT_SIZE 512        // nodes per bucket; requires N <= 65536 (pack: src<<9|l)
#define CHUNK 4096          // edges per block in binning phases
#define PAD_SLACK 4096      // per-bucket csr slack >= max pad (7*512=3584)
#define LSTR 264            // LDS row stride (bf16); 528B keeps 16B alignment, odd*16B breaks pow2

typedef __attribute__((ext_vector_type(8))) short short8;   // 8 bf16 MFMA A/B frag
typedef __attribute__((ext_vector_type(4))) float floatx4;  // MFMA C/D frag

// fp32 -> bf16 (RNE), branch-free; inputs finite
static __device__ __forceinline__ unsigned short f2b(float f) {
  unsigned u = __float_as_uint(f);
  unsigned r = (u + 0x7fffu + ((u >> 16) & 1u)) >> 16;
  return (unsigned short)r;
}

static __device__ __forceinline__ void unpack8(uint4 v, float* f) {
  f[0] = __uint_as_float(v.x << 16); f[1] = __uint_as_float(v.x & 0xffff0000u);
  f[2] = __uint_as_float(v.y << 16); f[3] = __uint_as_float(v.y & 0xffff0000u);
  f[4] = __uint_as_float(v.z << 16); f[5] = __uint_as_float(v.z & 0xffff0000u);
  f[6] = __uint_as_float(v.w << 16); f[7] = __uint_as_float(v.w & 0xffff0000u);
}

static __device__ __forceinline__ void acc_fma(float* acc, uint4 v, float w) {
  float g[8];
  unpack8(v, g);
#pragma unroll
  for (int d = 0; d < 8; ++d) acc[d] = fmaf(g[d], w, acc[d]);
}

// ================= CSR build (separate dispatches; no grid.sync) =================

// P1a: bucket histogram (LDS-staged)
__global__ __launch_bounds__(256) void bin_hist_kernel(const int* __restrict__ dst,
                                                       int* __restrict__ bkt_cnt,
                                                       int E, int nbkt) {
  __shared__ int hist[128];
  const int tid = threadIdx.x;
  if (tid < nbkt) hist[tid] = 0;
  __syncthreads();
  const int base = blockIdx.x * CHUNK;
  const int end = min(base + CHUNK, E);
  for (int e = base + tid; e < end; e += 256)
    atomicAdd(&hist[dst[e] >> BKT_SHIFT], 1);
  __syncthreads();
  if (tid < nbkt && hist[tid] > 0) atomicAdd(&bkt_cnt[tid], hist[tid]);
}

// P1b: exclusive scan of bucket counts (nbkt <= 128); init cursors; dinv sentinel
__global__ __launch_bounds__(128) void bkt_scan_kernel(const int* __restrict__ bkt_cnt,
                                                       int* __restrict__ bkt_start,
                                                       int* __restrict__ bkt_cursor,
                                                       float* __restrict__ dinv,
                                                       int nbkt, int E, int N) {
  __shared__ int w0tot;
  const int tid = threadIdx.x;
  const int lane = tid & 63, wid = tid >> 6;
  int v = (tid < nbkt) ? bkt_cnt[tid] : 0;
  int incl = v;
#pragma unroll
  for (int off = 1; off < 64; off <<= 1) {
    int t = __shfl_up(incl, off);
    if (lane >= off) incl += t;
  }
  if (wid == 0 && lane == 63) w0tot = incl;
  __syncthreads();
  int ex = incl - v + (wid ? w0tot : 0);
  if (tid < nbkt) { bkt_start[tid] = ex; bkt_cursor[tid] = ex; }
  if (tid == 0) { bkt_start[nbkt] = E; dinv[N] = 0.f; }  // sentinel: pad slots weight 0
}

// P1c: bin edges into bucket-contiguous runs, packed u = (src<<9)|(dst&511)
__global__ __launch_bounds__(256) void bin_scatter_kernel(const int* __restrict__ src,
                                                          const int* __restrict__ dst,
                                                          int* __restrict__ bkt_cursor,
                                                          int* __restrict__ ebuf,
                                                          int E, int nbkt) {
  __shared__ int hist[128];
  __shared__ int bbase[128];
  const int tid = threadIdx.x;
  if (tid < nbkt) hist[tid] = 0;
  __syncthreads();
  const int base = blockIdx.x * CHUNK;
  const int end = min(base + CHUNK, E);
  for (int e = base + tid; e < end; e += 256)
    atomicAdd(&hist[dst[e] >> BKT_SHIFT], 1);
  __syncthreads();
  if (tid < nbkt) {
    int c = hist[tid];
    bbase[tid] = c > 0 ? atomicAdd(&bkt_cursor[tid], c) : 0;
    hist[tid] = 0;  // reuse as intra-block cursor
  }
  __syncthreads();
  for (int e = base + tid; e < end; e += 256) {
    int d = dst[e];
    int b = d >> BKT_SHIFT;
    int off = atomicAdd(&hist[b], 1);
    ebuf[bbase[b] + off] = (src[e] << BKT_SHIFT) | (d & (BKT_SIZE - 1));
  }
}

// P2 (fused): per-bucket degree hist -> dinv + rowse; place src into padded CSR; pad fill.
__global__ __launch_bounds__(256) void bucket_build_kernel(const int* __restrict__ ebuf,
                                                           const int* __restrict__ bkt_start,
                                                           float* __restrict__ dinv,
                                                           int2* __restrict__ rowse,
                                                           int* __restrict__ csr,
                                                           int N, int nbkt) {
  __shared__ int hist[BKT_SIZE];
  __shared__ int srs[BKT_SIZE];
  __shared__ int wsums[4];
  const int b = blockIdx.x;
  const int tid = threadIdx.x;
  const int node0 = b << BKT_SHIFT;
  const int nloc = min(BKT_SIZE, N - node0);
  const int ebeg = bkt_start[b], eend = bkt_start[b + 1];

  hist[tid] = 0; hist[tid + 256] = 0;
  __syncthreads();
  for (int e = ebeg + tid; e < eend; e += 256)
    atomicAdd(&hist[ebuf[e] & (BKT_SIZE - 1)], 1);
  __syncthreads();

  // padded (multiple-of-8) 512-wide exclusive scan, 2 elems/thread
  const int h0 = hist[2 * tid], h1 = hist[2 * tid + 1];
  const int p0 = (h0 + 7) & ~7, p1 = (h1 + 7) & ~7;
  const int s = p0 + p1;
  const int lane = tid & 63, wid = tid >> 6;
  int incl = s;
#pragma unroll
  for (int off = 1; off < 64; off <<= 1) {
    int t = __shfl_up(incl, off);
    if (lane >= off) incl += t;
  }
  if (lane == 63) wsums[wid] = incl;
  __syncthreads();
  int wex = 0;
  for (int w = 0; w < wid; ++w) wex += wsums[w];
  const int ex = wex + incl - s;
  const int base = ebeg + b * PAD_SLACK;
  if (2 * tid < nloc) {
    int st = base + ex;
    dinv[node0 + 2 * tid] = rsqrtf((float)(h0 + 1));
    rowse[node0 + 2 * tid] = make_int2(st, st + p0);
    srs[2 * tid] = st;
  }
  if (2 * tid + 1 < nloc) {
    int st = base + ex + p0;
    dinv[node0 + 2 * tid + 1] = rsqrtf((float)(h1 + 1));
    rowse[node0 + 2 * tid + 1] = make_int2(st, st + p1);
    srs[2 * tid + 1] = st;
  }
  hist[2 * tid] = 0; hist[2 * tid + 1] = 0;  // reuse as per-node cursors
  __syncthreads();

  for (int e = ebeg + tid; e < eend; e += 256) {
    int u = ebuf[e];
    int l = u & (BKT_SIZE - 1);
    int pos = atomicAdd(&hist[l], 1);
    csr[srs[l] + pos] = u >> BKT_SHIFT;
  }
  __syncthreads();
  for (int l = tid; l < nloc; l += 256) {
    int deg = hist[l];
    int p = (deg + 7) & ~7;
    int s0 = srs[l];
    for (int q = s0 + deg; q < s0 + p; ++q) csr[q] = N;  // sentinel: dinv[N]=0
  }
}

// ================= fused conversions: x->bf16, W1->Wt1, W2->Wt2 =================

__global__ __launch_bounds__(256) void prep_kernel(const float4* __restrict__ x4,
                                                   unsigned short* __restrict__ xb, int n4,
                                                   const float* __restrict__ W1,
                                                   unsigned short* __restrict__ Wt1,
                                                   const float* __restrict__ W2,
                                                   unsigned short* __restrict__ Wt2) {
  const int nxblk = (n4 + 255) / 256;
  const int bid = blockIdx.x;
  if (bid < nxblk) {
    int i = bid * 256 + threadIdx.x;
    if (i >= n4) return;
    float4 v = x4[i];
    ushort4 o;
    o.x = f2b(v.x); o.y = f2b(v.y); o.z = f2b(v.z); o.w = f2b(v.w);
    *(ushort4*)(xb + (size_t)i * 4) = o;
  } else if (bid < nxblk + 128) {
    // W1[K=128][N=256] -> Wt1[N][K]
    int e = (bid - nxblk) * 256 + threadIdx.x;
    int k = e >> 8, n = e & 255;
    Wt1[(size_t)n * D_IN + k] = f2b(W1[e]);
  } else {
    // W2[K=256][N=128] -> Wt2[N][K]
    int e = (bid - nxblk - 128) * 256 + threadIdx.x;
    int k = e >> 7, n = e & 127;
    Wt2[(size_t)n * HID + k] = f2b(W2[e]);
  }
}

// ================= fused MFMA GEMM1+GEMM2: T = relu(A@W1+b1) @ W2 =================
// 64 rows/block, 4 waves, COLUMN-SPLIT: phase 1 wave w computes h-cols [w*64,w*64+64)
// for all 64 rows (4 row-groups x 4 col-tiles); h -> shared LDS tile; barrier;
// phase 2 wave w computes t-cols [w*32,w*32+32) with A-frags from LDS (ds_read_b128,
// low latency) and 16 B-loads from L2. Epilogue: t -> LDS -> coalesced uint4 stores.
// Per-wave global loads: 48 (vs 128 in the wave-private version that latency-bound R10).
// Layouts (verified m89/m91): A[m=lane&15][k=quad*8+j]; B[k=quad*8+j][n=lane&15];
// C/D: row=quad*4+reg, col=lane&15.

__global__ __launch_bounds__(256) void gemm12_kernel(const unsigned short* __restrict__ A,
                                                     const unsigned short* __restrict__ Wt1,
                                                     const float* __restrict__ b1,
                                                     const unsigned short* __restrict__ Wt2,
                                                     unsigned short* __restrict__ T, int M) {
  __shared__ unsigned short hs[64][LSTR];
  const int tid = threadIdx.x;
  const int wave = tid >> 6;
  const int lane = tid & 63;
  const int quad = lane >> 4;
  const int l16 = lane & 15;
  const int row0 = blockIdx.x * 64;

  // ---- phase 1: hs[0..63][wave*64 .. +64) = relu(A@W1 + b1) ----
  const short8* ap[4];
#pragma unroll
  for (int g = 0; g < 4; ++g) {
    int r = row0 + g * 16 + l16;
    if (r >= M) r = M - 1;  // clamp; final stores guarded
    ap[g] = (const short8*)(A + (size_t)r * D_IN + quad * 8);
  }
  // Wt1 row = 16 short8; col-tile t -> rows wave*64 + t*16 + l16
  const short8* bp1 = (const short8*)(Wt1 + (size_t)(wave * 64 + l16) * D_IN + quad * 8);

  floatx4 acc1[4][4];  // [row-group][col-tile]
#pragma unroll
  for (int g = 0; g < 4; ++g)
#pragma unroll
    for (int t = 0; t < 4; ++t) acc1[g][t] = floatx4{0.f, 0.f, 0.f, 0.f};

#pragma unroll
  for (int kt = 0; kt < 4; ++kt) {  // K = 128
    short8 a0 = ap[0][kt * 4], a1 = ap[1][kt * 4], a2 = ap[2][kt * 4], a3 = ap[3][kt * 4];
#pragma unroll
    for (int t = 0; t < 4; ++t) {
      short8 b = bp1[kt * 4 + t * 256];  // t*16 rows * 16 short8/row
      acc1[0][t] = __builtin_amdgcn_mfma_f32_16x16x32_bf16(a0, b, acc1[0][t], 0, 0, 0);
      acc1[1][t] = __builtin_amdgcn_mfma_f32_16x16x32_bf16(a1, b, acc1[1][t], 0, 0, 0);
      acc1[2][t] = __builtin_amdgcn_mfma_f32_16x16x32_bf16(a2, b, acc1[2][t], 0, 0, 0);
      acc1[3][t] = __builtin_amdgcn_mfma_f32_16x16x32_bf16(a3, b, acc1[3][t], 0, 0, 0);
    }
  }
#pragma unroll
  for (int t = 0; t < 4; ++t) {
    const float bv = b1[wave * 64 + t * 16 + l16];
#pragma unroll
    for (int g = 0; g < 4; ++g)
#pragma unroll
      for (int r = 0; r < 4; ++r) {
        float v = acc1[g][t][r] + bv;
        v = v > 0.f ? v : 0.f;
        hs[g * 16 + quad * 4 + r][wave * 64 + t * 16 + l16] = f2b(v);
      }
  }
  __syncthreads();

  // ---- phase 2: t[0..63][wave*32 .. +32) = hs @ Wt2^T ----
  const short8* bp2 = (const short8*)(Wt2 + (size_t)(wave * 32 + l16) * HID + quad * 8);
  floatx4 acc2[4][2];
#pragma unroll
  for (int g = 0; g < 4; ++g)
#pragma unroll
    for (int t = 0; t < 2; ++t) acc2[g][t] = floatx4{0.f, 0.f, 0.f, 0.f};

#pragma unroll
  for (int kt = 0; kt < 8; ++kt) {  // K = 256
    short8 a0 = *(const short8*)&hs[0 * 16 + l16][kt * 32 + quad * 8];
    short8 a1 = *(const short8*)&hs[1 * 16 + l16][kt * 32 + quad * 8];
    short8 a2 = *(const short8*)&hs[2 * 16 + l16][kt * 32 + quad * 8];
    short8 a3 = *(const short8*)&hs[3 * 16 + l16][kt * 32 + quad * 8];
#pragma unroll
    for (int t = 0; t < 2; ++t) {
      short8 b = bp2[kt * 4 + t * 512];  // t*16 rows * 32 short8/row
      acc2[0][t] = __builtin_amdgcn_mfma_f32_16x16x32_bf16(a0, b, acc2[0][t], 0, 0, 0);
      acc2[1][t] = __builtin_amdgcn_mfma_f32_16x16x32_bf16(a1, b, acc2[1][t], 0, 0, 0);
      acc2[2][t] = __builtin_amdgcn_mfma_f32_16x16x32_bf16(a2, b, acc2[2][t], 0, 0, 0);
      acc2[3][t] = __builtin_amdgcn_mfma_f32_16x16x32_bf16(a3, b, acc2[3][t], 0, 0, 0);
    }
  }
  __syncthreads();  // all waves done reading hs before overwrite

  // t-tile -> LDS (cols wave*32..+32)
#pragma unroll
  for (int t = 0; t < 2; ++t)
#pragma unroll
    for (int g = 0; g < 4; ++g)
#pragma unroll
      for (int r = 0; r < 4; ++r)
        hs[g * 16 + quad * 4 + r][wave * 32 + t * 16 + l16] = f2b(acc2[g][t][r]);
  __syncthreads();

  // coalesced store: 64 rows x 128 cols bf16; 16 lanes x 16B = one 256B row
#pragma unroll
  for (int i = 0; i < 4; ++i) {
    const int r = i * 16 + (tid >> 4);
    const int c = (tid & 15) * 8;
    const int row = row0 + r;
    uint4 v = *(const uint4*)&hs[r][c];
    if (row < M) *(uint4*)&T[(size_t)row * D_IN + c] = v;
  }
}

// ================= CSR aggregation (D=128 bf16), unroll-8, padded rows =================
// 16 lanes/node (uint4 = 8 bf16 per gather), 16 nodes/block; csr = src only (4B),
// w = dinv[s]*dinv[d] recomputed (dinv L2-resident); pad sentinel N has dinv 0.

template<bool SKIP_BIAS>
__global__ __launch_bounds__(256) void agg_kernel(const uint4* __restrict__ Hq,
                                                  const int2* __restrict__ rowse,
                                                  const int* __restrict__ csr,
                                                  const float* __restrict__ dinv,
                                                  const float* __restrict__ skip,
                                                  const float* __restrict__ bias,
                                                  void* __restrict__ OUT, int n) {
  const int lane = threadIdx.x & 15;
  const int node = blockIdx.x * 16 + (threadIdx.x >> 4);
  if (node >= n) return;

  const float dv = dinv[node];
  float acc[8];
  {
    uint4 sv = Hq[(size_t)node * 16 + lane];
    float f[8];
    unpack8(sv, f);
    const float ws = dv * dv;
#pragma unroll
    for (int d = 0; d < 8; ++d) acc[d] = f[d] * ws;
  }

  const int2 se = rowse[node];
  for (int j = se.x; j < se.y; j += 8) {
    int4 c0 = *(const int4*)(csr + j);
    int4 c1 = *(const int4*)(csr + j + 4);
    float w0 = dinv[c0.x] * dv, w1 = dinv[c0.y] * dv;
    float w2 = dinv[c0.z] * dv, w3 = dinv[c0.w] * dv;
    float w4 = dinv[c1.x] * dv, w5 = dinv[c1.y] * dv;
    float w6 = dinv[c1.z] * dv, w7 = dinv[c1.w] * dv;
    uint4 v0 = Hq[(size_t)c0.x * 16 + lane];
    uint4 v1 = Hq[(size_t)c0.y * 16 + lane];
    uint4 v2 = Hq[(size_t)c0.z * 16 + lane];
    uint4 v3 = Hq[(size_t)c0.w * 16 + lane];
    uint4 v4 = Hq[(size_t)c1.x * 16 + lane];
    uint4 v5 = Hq[(size_t)c1.y * 16 + lane];
    uint4 v6 = Hq[(size_t)c1.z * 16 + lane];
    uint4 v7 = Hq[(size_t)c1.w * 16 + lane];
    acc_fma(acc, v0, w0);
    acc_fma(acc, v1, w1);
    acc_fma(acc, v2, w2);
    acc_fma(acc, v3, w3);
    acc_fma(acc, v4, w4);
    acc_fma(acc, v5, w5);
    acc_fma(acc, v6, w6);
    acc_fma(acc, v7, w7);
  }

  if (SKIP_BIAS) {
    const float* sp = skip + (size_t)node * 128 + lane * 8;
    const float* bp = bias + lane * 8;
    float4 s0 = *(const float4*)sp, s1 = *(const float4*)(sp + 4);
    float4 b0 = *(const float4*)bp, b1 = *(const float4*)(bp + 4);
    float* op = (float*)OUT + (size_t)node * 128 + lane * 8;
    *(float4*)op = make_float4(acc[0] + s0.x + b0.x, acc[1] + s0.y + b0.y,
                               acc[2] + s0.z + b0.z, acc[3] + s0.w + b0.w);
    *(float4*)(op + 4) = make_float4(acc[4] + s1.x + b1.x, acc[5] + s1.y + b1.y,
                                     acc[6] + s1.z + b1.z, acc[7] + s1.w + b1.w);
  } else {
    uint4 o;
    o.x = (unsigned)f2b(acc[0]) | ((unsigned)f2b(acc[1]) << 16);
    o.y = (unsigned)f2b(acc[2]) | ((unsigned)f2b(acc[3]) << 16);
    o.z = (unsigned)f2b(acc[4]) | ((unsigned)f2b(acc[5]) << 16);
    o.w = (unsigned)f2b(acc[6]) | ((unsigned)f2b(acc[7]) << 16);
    ((uint4*)OUT)[(size_t)node * 16 + lane] = o;
  }
}

// ================= launch =================

extern "C" void kernel_launch(void* const* d_in, const int* in_sizes, int n_in,
                              void* d_out, int out_size, void* d_ws, size_t ws_size,
                              hipStream_t stream) {
  const float* x  = (const float*)d_in[0];
  const int*   ei = (const int*)d_in[1];
  const float* W1 = (const float*)d_in[2];
  const float* b1 = (const float*)d_in[3];
  const float* W2 = (const float*)d_in[4];
  const float* b2 = (const float*)d_in[5];
  float* out = (float*)d_out;

  const int N = in_sizes[0] / D_IN;      // requires N <= 65536 (packed ebuf)
  const int E = in_sizes[1] / 2;
  const int* srcA = ei;
  const int* dstA = ei + E;
  const int NBKT = (N + BKT_SIZE - 1) >> BKT_SHIFT;  // 98 for N=50000
  const int NCHUNK = (E + CHUNK - 1) / CHUNK;        // 391

  // ---- workspace (256B aligned) ----
  char* ws = (char*)d_ws;
  size_t off = 0;
  auto alloc = [&](size_t bytes) { void* p = ws + off; off = (off + bytes + 255) & ~(size_t)255; return p; };
  int*            bkt_cnt    = (int*)           alloc((size_t)NBKT * 4);
  int*            bkt_start  = (int*)           alloc((size_t)(NBKT + 1) * 4);
  int*            bkt_cursor = (int*)           alloc((size_t)NBKT * 4);
  float*          dinv       = (float*)         alloc((size_t)(N + 1) * 4);  // +sentinel
  int2*           rowse      = (int2*)          alloc((size_t)N * 8);
  int*            ebuf       = (int*)           alloc((size_t)E * 4);
  int*            csr        = (int*)           alloc(((size_t)E + (size_t)NBKT * PAD_SLACK) * 4);
  unsigned short* xb         = (unsigned short*)alloc((size_t)(N + 1) * D_IN * 2);
  unsigned short* aggx       = (unsigned short*)alloc((size_t)N * D_IN * 2);
  unsigned short* tb         = (unsigned short*)alloc((size_t)(N + 1) * D_IN * 2);
  unsigned short* Wt1        = (unsigned short*)alloc((size_t)D_IN * HID * 2);
  unsigned short* Wt2        = (unsigned short*)alloc((size_t)D_IN * HID * 2);

  // 1) CSR build: bucket hist -> scan -> bin -> fused per-bucket build
  hipMemsetAsync(bkt_cnt, 0, (size_t)NBKT * 4, stream);
  bin_hist_kernel<<<NCHUNK, 256, 0, stream>>>(dstA, bkt_cnt, E, NBKT);
  bkt_scan_kernel<<<1, 128, 0, stream>>>(bkt_cnt, bkt_start, bkt_cursor, dinv, NBKT, E, N);
  bin_scatter_kernel<<<NCHUNK, 256, 0, stream>>>(srcA, dstA, bkt_cursor, ebuf, E, NBKT);
  bucket_build_kernel<<<NBKT, 256, 0, stream>>>(ebuf, bkt_start, dinv, rowse, csr, N, NBKT);

  // 2) conversions
  {
    const int n4 = N * D_IN / 4;
    prep_kernel<<<(n4 + 255) / 256 + 256, 256, 0, stream>>>((const float4*)x, xb, n4,
                                                            W1, Wt1, W2, Wt2);
  }
  // 3) aggx = Â x
  agg_kernel<false><<<(N + 15) / 16, 256, 0, stream>>>((const uint4*)xb, rowse, csr,
                                                       dinv, nullptr, nullptr, aggx, N);
  // 4) tb = relu(aggx @ W1 + b1) @ W2   (fused; h lives only in LDS)
  gemm12_kernel<<<(N + 63) / 64, 256, 0, stream>>>(aggx, Wt1, b1, Wt2, tb, N);
  // 5) out = Â tb + x + b2
  agg_kernel<true><<<(N + 15) / 16, 256, 0, stream>>>((const uint4*)tb, rowse, csr,
                                                      dinv, x, b2, out, N);
}